// Round 8
// baseline (151.089 us; speedup 1.0000x reference)
//
#include <hip/hip_runtime.h>

typedef __bf16 bf16;
typedef __bf16 bf16x8 __attribute__((ext_vector_type(8)));
typedef __bf16 bf16x4 __attribute__((ext_vector_type(4)));
typedef __bf16 bf16x2 __attribute__((ext_vector_type(2)));
typedef float  f32x4  __attribute__((ext_vector_type(4)));
typedef unsigned int u32;
typedef u32 u32x4 __attribute__((ext_vector_type(4)));

#define NN_  320
#define CZ_  128
#define H_   4
#define CH_  32

__device__ __forceinline__ u32 pack_bf16(float a, float b) {
    bf16x2 t; t[0] = (bf16)a; t[1] = (bf16)b;
    return __builtin_bit_cast(u32, t);
}

// ---------------------------------------------------------------------------
// Kernel 1: QKVG projections. grid 800 x 512 threads (8 waves x 16 rows).
// Q: [n][h][q][32] bf16 (pre-scaled 1/sqrt(32)); K: [n][h][kv][32];
// V: [n][h][32][kv] (transposed, via swapped mfma); G: [m][128] sigmoid.
// ---------------------------------------------------------------------------
__global__ __launch_bounds__(512) void qkvg_kernel(
    const float* __restrict__ x,
    const float* __restrict__ wq, const float* __restrict__ wk,
    const float* __restrict__ wv, const float* __restrict__ wg,
    const float* __restrict__ bg,
    bf16* __restrict__ Qp, bf16* __restrict__ Kp,
    bf16* __restrict__ Vp, bf16* __restrict__ Gp)
{
    __shared__ bf16 wl[128][136];   // transposed weight wl[j][k], stride 272B
    const int tid  = threadIdx.x;
    const int lane = tid & 63, wid = tid >> 6;
    const int l15  = lane & 15, l4 = lane >> 4;
    const int m0   = blockIdx.x << 7;   // 128 rows per block

    // x row fragments straight to registers (fp32 -> bf16)
    const int arow = m0 + wid * 16 + l15;
    bf16x8 xf[4];
    #pragma unroll
    for (int ks = 0; ks < 4; ++ks) {
        float4 f0 = *reinterpret_cast<const float4*>(x + (size_t)arow * CZ_ + ks * 32 + l4 * 8);
        float4 f1 = *reinterpret_cast<const float4*>(x + (size_t)arow * CZ_ + ks * 32 + l4 * 8 + 4);
        bf16x8 t;
        t[0]=(bf16)f0.x; t[1]=(bf16)f0.y; t[2]=(bf16)f0.z; t[3]=(bf16)f0.w;
        t[4]=(bf16)f1.x; t[5]=(bf16)f1.y; t[6]=(bf16)f1.z; t[7]=(bf16)f1.w;
        xf[ks] = t;
    }

    // row decompositions (blocks can cross n boundaries: 128 does not divide 320)
    int nQ[4], qQ[4];
    #pragma unroll
    for (int r = 0; r < 4; ++r) {
        int m = m0 + wid * 16 + l4 * 4 + r;
        nQ[r] = m / NN_; qQ[r] = m - nQ[r] * NN_;
    }
    const int nV = arow / NN_, qV = arow - nV * NN_;

    const float* Ws[4] = {wq, wk, wv, wg};
    #pragma unroll
    for (int mat = 0; mat < 4; ++mat) {
        __syncthreads();
        const float* w = Ws[mat];
        // stage transposed bf16 weight: wl[j][k] = w[k][j], b64 LDS writes
        #pragma unroll
        for (int it = 0; it < 8; ++it) {
            int u  = tid + (it << 9);        // 4096 units
            int j  = u & 127, k4 = u >> 7;   // k4: 0..31
            bf16x4 t;
            t[0] = (bf16)w[(k4 * 4 + 0) * CZ_ + j];
            t[1] = (bf16)w[(k4 * 4 + 1) * CZ_ + j];
            t[2] = (bf16)w[(k4 * 4 + 2) * CZ_ + j];
            t[3] = (bf16)w[(k4 * 4 + 3) * CZ_ + j];
            *reinterpret_cast<bf16x4*>(&wl[j][k4 * 4]) = t;
        }
        __syncthreads();

        f32x4 zero = {0.f, 0.f, 0.f, 0.f};
        f32x4 acc[8];
        #pragma unroll
        for (int ct = 0; ct < 8; ++ct) acc[ct] = zero;

        #pragma unroll
        for (int ks = 0; ks < 4; ++ks) {
            #pragma unroll
            for (int ct = 0; ct < 8; ++ct) {
                bf16x8 wf = *reinterpret_cast<const bf16x8*>(&wl[ct * 16 + l15][ks * 32 + l4 * 8]);
                if (mat == 2)  // swapped: D[cout][m] so the V^T store coalesces
                    acc[ct] = __builtin_amdgcn_mfma_f32_16x16x32_bf16(wf, xf[ks], acc[ct], 0, 0, 0);
                else
                    acc[ct] = __builtin_amdgcn_mfma_f32_16x16x32_bf16(xf[ks], wf, acc[ct], 0, 0, 0);
            }
        }

        if (mat == 0) {
            #pragma unroll
            for (int ct = 0; ct < 8; ++ct) {
                const int cout = ct * 16 + l15, hh = cout >> 5, cc = cout & 31;
                #pragma unroll
                for (int r = 0; r < 4; ++r)
                    Qp[(size_t)((nQ[r] * H_ + hh) * NN_ + qQ[r]) * CH_ + cc] =
                        (bf16)(acc[ct][r] * 0.17677669529663687f);
            }
        } else if (mat == 1) {
            #pragma unroll
            for (int ct = 0; ct < 8; ++ct) {
                const int cout = ct * 16 + l15, hh = cout >> 5, cc = cout & 31;
                #pragma unroll
                for (int r = 0; r < 4; ++r)
                    Kp[(size_t)((nQ[r] * H_ + hh) * NN_ + qQ[r]) * CH_ + cc] = (bf16)acc[ct][r];
            }
        } else if (mat == 2) {
            // D row = cout = ct*16 + l4*4 + r; D col = m-local = l15 (arow)
            #pragma unroll
            for (int ct = 0; ct < 8; ++ct) {
                #pragma unroll
                for (int r = 0; r < 4; ++r) {
                    const int cout = ct * 16 + l4 * 4 + r, hh = cout >> 5, cc = cout & 31;
                    Vp[(size_t)((nV * H_ + hh) * CH_ + cc) * NN_ + qV] = (bf16)acc[ct][r];
                }
            }
        } else {
            #pragma unroll
            for (int ct = 0; ct < 8; ++ct) {
                const int cout = ct * 16 + l15;
                const float bgj = bg[cout];
                #pragma unroll
                for (int r = 0; r < 4; ++r) {
                    float t = acc[ct][r] + bgj;
                    Gp[(size_t)(m0 + wid * 16 + l4 * 4 + r) * CZ_ + cout] =
                        (bf16)(1.0f / (1.0f + __expf(-t)));
                }
            }
        }
    }
}

// ---------------------------------------------------------------------------
// Kernel 2: fused attention + gating. grid 2560, 320 threads = 5 waves.
// Block = (n, h, q-half of 160). K (320x32) and V^T (32x320) staged once into
// padded LDS; wave = 32 q rows (2 x 16-q groups FOLDED: every K/V LDS read
// feeds MFMAs for both q-groups). Bias is pipelined 2 tp-iterations deep in
// two STATIC register buffers (bA/bB). XCD chunking pins one h per XCD so the
// 400KB bias slice is L2-resident. __launch_bounds__(320,4): 16 waves/CU ->
// 128-VGPR budget for the ~120 live regs (default budget spills this kernel).
// No max subtraction (|s| <~ 6); sigma-permuted zero-shuffle PV.
// Overwrites Gp with o*g (bf16).
// ---------------------------------------------------------------------------
__global__ __launch_bounds__(320, 4) void attn_kernel(
    const bf16* __restrict__ Qp, const bf16* __restrict__ Kp,
    const bf16* __restrict__ Vp, bf16* __restrict__ Gp,
    const float* __restrict__ bias)
{
    __shared__ bf16 Kl[320][40];    // 80B rows
    __shared__ bf16 Vl[32][328];    // 656B rows
    const int tid  = threadIdx.x;
    const int lane = tid & 63;
    const int wid  = tid >> 6;            // 0..4
    const int l15  = lane & 15, l4 = lane >> 4;
    // XCD chunking: lin h-major => each XCD covers exactly one h value.
    const int gid = blockIdx.x;
    const int lin = (gid & 7) * 320 + (gid >> 3);
    const int h   = lin / 640;
    const int rem = lin - h * 640;
    const int n   = rem >> 1;
    const int qh  = (rem & 1) * 160;

    const size_t nh = (size_t)(n * H_ + h);
    const bf16* Kh = Kp + nh * NN_ * CH_;
    const bf16* Vh = Vp + nh * CH_ * NN_;
    const bf16* Qh = Qp + nh * NN_ * CH_;

    // one-shot cooperative staging: 1280 16B chunks each for K and V^T
    #pragma unroll
    for (int i = 0; i < 4; ++i) {
        int c  = tid + i * 320;
        int kr = c >> 2, kc = (c & 3) * 8;
        *reinterpret_cast<bf16x8*>(&Kl[kr][kc]) =
            *reinterpret_cast<const bf16x8*>(Kh + kr * CH_ + kc);
        int vr = c / 40, vc = (c % 40) * 8;
        *reinterpret_cast<bf16x8*>(&Vl[vr][vc]) =
            *reinterpret_cast<const bf16x8*>(Vh + vr * NN_ + vc);
    }
    __syncthreads();

    const int qb0 = qh + wid * 32;
    const int qb1 = qb0 + 16;
    const bf16x8 qf0 = *reinterpret_cast<const bf16x8*>(&Qh[(qb0 + l15) * CH_ + l4 * 8]);
    const bf16x8 qf1 = *reinterpret_cast<const bf16x8*>(&Qh[(qb1 + l15) * CH_ + l4 * 8]);
    const float* bp0 = bias + ((size_t)h * NN_ + qb0 + l15) * NN_ + l4 * 4;
    const float* bp1 = bias + ((size_t)h * NN_ + qb1 + l15) * NN_ + l4 * 4;
    const size_t gb0 = ((size_t)n * NN_ + qb0 + l15) * CZ_ + h * CH_;
    const size_t gb1 = ((size_t)n * NN_ + qb1 + l15) * CZ_ + h * CH_;
    const bf16x4 g00 = *reinterpret_cast<const bf16x4*>(&Gp[gb0 + l4 * 4]);
    const bf16x4 g01 = *reinterpret_cast<const bf16x4*>(&Gp[gb0 + 16 + l4 * 4]);
    const bf16x4 g10 = *reinterpret_cast<const bf16x4*>(&Gp[gb1 + l4 * 4]);
    const bf16x4 g11 = *reinterpret_cast<const bf16x4*>(&Gp[gb1 + 16 + l4 * 4]);

    const f32x4 zero = {0.f, 0.f, 0.f, 0.f};
    f32x4 o00 = zero, o01 = zero, o10 = zero, o11 = zero;
    float ls0 = 0.f, ls1 = 0.f;

    // 2-deep bias pipeline in STATIC buffers (no runtime indexing -> regs)
    float4 bA[4], bB[4];
    bA[0] = *reinterpret_cast<const float4*>(bp0);
    bA[1] = *reinterpret_cast<const float4*>(bp0 + 16);
    bA[2] = *reinterpret_cast<const float4*>(bp1);
    bA[3] = *reinterpret_cast<const float4*>(bp1 + 16);
    bB[0] = *reinterpret_cast<const float4*>(bp0 + 32);
    bB[1] = *reinterpret_cast<const float4*>(bp0 + 48);
    bB[2] = *reinterpret_cast<const float4*>(bp1 + 32);
    bB[3] = *reinterpret_cast<const float4*>(bp1 + 48);

#define ATTN_TP(TP, BUF, PRE)                                                      \
    {                                                                              \
        const int kvm = (TP) * 32;                                                 \
        bf16x8 kf0 = *reinterpret_cast<const bf16x8*>(&Kl[kvm + l15][l4 * 8]);     \
        bf16x8 kf1 = *reinterpret_cast<const bf16x8*>(&Kl[kvm + 16 + l15][l4 * 8]);\
        f32x4 s00 = __builtin_amdgcn_mfma_f32_16x16x32_bf16(kf0, qf0, zero, 0, 0, 0); \
        f32x4 s01 = __builtin_amdgcn_mfma_f32_16x16x32_bf16(kf1, qf0, zero, 0, 0, 0); \
        f32x4 s10 = __builtin_amdgcn_mfma_f32_16x16x32_bf16(kf0, qf1, zero, 0, 0, 0); \
        f32x4 s11 = __builtin_amdgcn_mfma_f32_16x16x32_bf16(kf1, qf1, zero, 0, 0, 0); \
        float e0 = __expf(s00[0] + BUF[0].x);                                      \
        float e1 = __expf(s00[1] + BUF[0].y);                                      \
        float e2 = __expf(s00[2] + BUF[0].z);                                      \
        float e3 = __expf(s00[3] + BUF[0].w);                                      \
        float e4 = __expf(s01[0] + BUF[1].x);                                      \
        float e5 = __expf(s01[1] + BUF[1].y);                                      \
        float e6 = __expf(s01[2] + BUF[1].z);                                      \
        float e7 = __expf(s01[3] + BUF[1].w);                                      \
        ls0 += ((e0 + e1) + (e2 + e3)) + ((e4 + e5) + (e6 + e7));                  \
        u32x4 w0;                                                                  \
        w0[0] = pack_bf16(e0, e1); w0[1] = pack_bf16(e2, e3);                      \
        w0[2] = pack_bf16(e4, e5); w0[3] = pack_bf16(e6, e7);                      \
        bf16x8 pf0 = __builtin_bit_cast(bf16x8, w0);                               \
        float f0 = __expf(s10[0] + BUF[2].x);                                      \
        float f1 = __expf(s10[1] + BUF[2].y);                                      \
        float f2 = __expf(s10[2] + BUF[2].z);                                      \
        float f3 = __expf(s10[3] + BUF[2].w);                                      \
        float f4 = __expf(s11[0] + BUF[3].x);                                      \
        float f5 = __expf(s11[1] + BUF[3].y);                                      \
        float f6 = __expf(s11[2] + BUF[3].z);                                      \
        float f7 = __expf(s11[3] + BUF[3].w);                                      \
        ls1 += ((f0 + f1) + (f2 + f3)) + ((f4 + f5) + (f6 + f7));                  \
        u32x4 w1;                                                                  \
        w1[0] = pack_bf16(f0, f1); w1[1] = pack_bf16(f2, f3);                      \
        w1[2] = pack_bf16(f4, f5); w1[3] = pack_bf16(f6, f7);                      \
        bf16x8 pf1 = __builtin_bit_cast(bf16x8, w1);                               \
        if (PRE) {  /* refill for TP+2: consumed two bodies later */               \
            BUF[0] = *reinterpret_cast<const float4*>(bp0 + ((TP) + 2) * 32);      \
            BUF[1] = *reinterpret_cast<const float4*>(bp0 + ((TP) + 2) * 32 + 16); \
            BUF[2] = *reinterpret_cast<const float4*>(bp1 + ((TP) + 2) * 32);      \
            BUF[3] = *reinterpret_cast<const float4*>(bp1 + ((TP) + 2) * 32 + 16); \
        }                                                                          \
        bf16x4 va0 = *reinterpret_cast<const bf16x4*>(&Vl[l15][kvm + l4 * 4]);     \
        bf16x4 va1 = *reinterpret_cast<const bf16x4*>(&Vl[l15][kvm + 16 + l4 * 4]);\
        bf16x4 vb0 = *reinterpret_cast<const bf16x4*>(&Vl[16 + l15][kvm + l4 * 4]);\
        bf16x4 vb1 = *reinterpret_cast<const bf16x4*>(&Vl[16 + l15][kvm + 16 + l4 * 4]); \
        bf16x8 vf0 = __builtin_shufflevector(va0, va1, 0, 1, 2, 3, 4, 5, 6, 7);    \
        bf16x8 vf1 = __builtin_shufflevector(vb0, vb1, 0, 1, 2, 3, 4, 5, 6, 7);    \
        o00 = __builtin_amdgcn_mfma_f32_16x16x32_bf16(vf0, pf0, o00, 0, 0, 0);     \
        o01 = __builtin_amdgcn_mfma_f32_16x16x32_bf16(vf1, pf0, o01, 0, 0, 0);     \
        o10 = __builtin_amdgcn_mfma_f32_16x16x32_bf16(vf0, pf1, o10, 0, 0, 0);     \
        o11 = __builtin_amdgcn_mfma_f32_16x16x32_bf16(vf1, pf1, o11, 0, 0, 0);     \
    }

    #pragma unroll 1
    for (int t2 = 0; t2 < 4; ++t2) {
        const int tp0 = 2 * t2;
        ATTN_TP(tp0, bA, true);
        ATTN_TP(tp0 + 1, bB, true);
    }
    ATTN_TP(8, bA, false);
    ATTN_TP(9, bB, false);
#undef ATTN_TP

    // final row-sum reduce (l4 groups hold disjoint kv subsets of each row)
    ls0 += __shfl_xor(ls0, 16);
    ls0 += __shfl_xor(ls0, 32);
    ls1 += __shfl_xor(ls1, 16);
    ls1 += __shfl_xor(ls1, 32);
    const float li0 = 1.0f / ls0;
    const float li1 = 1.0f / ls1;

    bf16x4 h00, h01, h10, h11;
    #pragma unroll
    for (int r = 0; r < 4; ++r) {
        h00[r] = (bf16)(o00[r] * li0 * (float)g00[r]);
        h01[r] = (bf16)(o01[r] * li0 * (float)g01[r]);
        h10[r] = (bf16)(o10[r] * li1 * (float)g10[r]);
        h11[r] = (bf16)(o11[r] * li1 * (float)g11[r]);
    }
    *reinterpret_cast<bf16x4*>(&Gp[gb0 + l4 * 4]) = h00;
    *reinterpret_cast<bf16x4*>(&Gp[gb0 + 16 + l4 * 4]) = h01;
    *reinterpret_cast<bf16x4*>(&Gp[gb1 + l4 * 4]) = h10;
    *reinterpret_cast<bf16x4*>(&Gp[gb1 + 16 + l4 * 4]) = h11;
}

// ---------------------------------------------------------------------------
// Kernel 3: out = og @ wo + bo (fp32). grid 800 x 512 threads.
// ---------------------------------------------------------------------------
__global__ __launch_bounds__(512) void oproj_kernel(
    const bf16* __restrict__ og, const float* __restrict__ wo,
    const float* __restrict__ bo, float* __restrict__ out)
{
    __shared__ bf16 wl[128][136];
    const int tid  = threadIdx.x;
    const int lane = tid & 63, wid = tid >> 6;
    const int l15  = lane & 15, l4 = lane >> 4;
    const int m0   = blockIdx.x << 7;

    #pragma unroll
    for (int it = 0; it < 8; ++it) {
        int u  = tid + (it << 9);
        int j  = u & 127, k4 = u >> 7;
        bf16x4 t;
        t[0] = (bf16)wo[(k4 * 4 + 0) * CZ_ + j];
        t[1] = (bf16)wo[(k4 * 4 + 1) * CZ_ + j];
        t[2] = (bf16)wo[(k4 * 4 + 2) * CZ_ + j];
        t[3] = (bf16)wo[(k4 * 4 + 3) * CZ_ + j];
        *reinterpret_cast<bf16x4*>(&wl[j][k4 * 4]) = t;
    }
    __syncthreads();

    const int arow = m0 + wid * 16 + l15;
    bf16x8 af[4];
    #pragma unroll
    for (int ks = 0; ks < 4; ++ks)
        af[ks] = *reinterpret_cast<const bf16x8*>(&og[(size_t)arow * CZ_ + ks * 32 + l4 * 8]);

    f32x4 zero = {0.f, 0.f, 0.f, 0.f};
    f32x4 acc[8];
    #pragma unroll
    for (int ct = 0; ct < 8; ++ct) acc[ct] = zero;
    #pragma unroll
    for (int ks = 0; ks < 4; ++ks)
        #pragma unroll
        for (int ct = 0; ct < 8; ++ct) {
            bf16x8 wf = *reinterpret_cast<const bf16x8*>(&wl[ct * 16 + l15][ks * 32 + l4 * 8]);
            acc[ct] = __builtin_amdgcn_mfma_f32_16x16x32_bf16(af[ks], wf, acc[ct], 0, 0, 0);
        }

    #pragma unroll
    for (int ct = 0; ct < 8; ++ct) {
        const int cout = ct * 16 + l15;
        const float bov = bo[cout];
        #pragma unroll
        for (int r = 0; r < 4; ++r)
            out[(size_t)(m0 + wid * 16 + l4 * 4 + r) * CZ_ + cout] = acc[ct][r] + bov;
    }
}

// ---------------------------------------------------------------------------
extern "C" void kernel_launch(void* const* d_in, const int* in_sizes, int n_in,
                              void* d_out, int out_size, void* d_ws, size_t ws_size,
                              hipStream_t stream) {
    (void)in_sizes; (void)n_in; (void)out_size; (void)ws_size;
    const float* x    = (const float*)d_in[0];
    const float* bias = (const float*)d_in[1];
    const float* wq   = (const float*)d_in[2];
    const float* wk   = (const float*)d_in[3];
    const float* wv   = (const float*)d_in[4];
    const float* wg   = (const float*)d_in[5];
    const float* bg   = (const float*)d_in[6];
    const float* wo   = (const float*)d_in[7];
    const float* bo   = (const float*)d_in[8];
    float* out = (float*)d_out;

    const size_t ELEMS = (size_t)NN_ * NN_ * CZ_;
    bf16* Qp = (bf16*)d_ws;          // 26.2 MB
    bf16* Gp = Qp + ELEMS;           // 26.2 MB
    bf16* Kp = (bf16*)d_out;         // scratch until oproj overwrites
    bf16* Vp = Kp + ELEMS;

    qkvg_kernel<<<dim3(800), 512, 0, stream>>>(x, wq, wk, wv, wg, bg, Qp, Kp, Vp, Gp);
    attn_kernel<<<dim3(2560), 320, 0, stream>>>(Qp, Kp, Vp, Gp, bias);
    oproj_kernel<<<dim3(800), 512, 0, stream>>>(Gp, wo, bo, out);
}

// Round 9
// 142.973 us; speedup vs baseline: 1.0568x; 1.0568x over previous
//
#include <hip/hip_runtime.h>

typedef __bf16 bf16;
typedef __bf16 bf16x8 __attribute__((ext_vector_type(8)));
typedef __bf16 bf16x4 __attribute__((ext_vector_type(4)));
typedef __bf16 bf16x2 __attribute__((ext_vector_type(2)));
typedef float  f32x4  __attribute__((ext_vector_type(4)));
typedef unsigned int u32;
typedef u32 u32x4 __attribute__((ext_vector_type(4)));

#define NN_  320
#define CZ_  128
#define H_   4
#define CH_  32
#define LOG2E_ 1.4426950408889634f

__device__ __forceinline__ u32 pack_bf16(float a, float b) {
    bf16x2 t; t[0] = (bf16)a; t[1] = (bf16)b;
    return __builtin_bit_cast(u32, t);
}

// ---------------------------------------------------------------------------
// Kernel 1: QKVG projections. grid 800 x 512 threads (8 waves x 16 rows).
// Q: [n][h][q][32] bf16, pre-scaled by log2e/sqrt(32) (exp2-domain scores);
// K: [n][h][kv][32]; V: [n][h][32][kv] (transposed); G: [m][128] sigmoid.
// ---------------------------------------------------------------------------
__global__ __launch_bounds__(512) void qkvg_kernel(
    const float* __restrict__ x,
    const float* __restrict__ wq, const float* __restrict__ wk,
    const float* __restrict__ wv, const float* __restrict__ wg,
    const float* __restrict__ bg,
    bf16* __restrict__ Qp, bf16* __restrict__ Kp,
    bf16* __restrict__ Vp, bf16* __restrict__ Gp)
{
    __shared__ bf16 wl[128][136];   // transposed weight wl[j][k], stride 272B
    const int tid  = threadIdx.x;
    const int lane = tid & 63, wid = tid >> 6;
    const int l15  = lane & 15, l4 = lane >> 4;
    const int m0   = blockIdx.x << 7;   // 128 rows per block

    // x row fragments straight to registers (fp32 -> bf16)
    const int arow = m0 + wid * 16 + l15;
    bf16x8 xf[4];
    #pragma unroll
    for (int ks = 0; ks < 4; ++ks) {
        float4 f0 = *reinterpret_cast<const float4*>(x + (size_t)arow * CZ_ + ks * 32 + l4 * 8);
        float4 f1 = *reinterpret_cast<const float4*>(x + (size_t)arow * CZ_ + ks * 32 + l4 * 8 + 4);
        bf16x8 t;
        t[0]=(bf16)f0.x; t[1]=(bf16)f0.y; t[2]=(bf16)f0.z; t[3]=(bf16)f0.w;
        t[4]=(bf16)f1.x; t[5]=(bf16)f1.y; t[6]=(bf16)f1.z; t[7]=(bf16)f1.w;
        xf[ks] = t;
    }

    // row decompositions (blocks can cross n boundaries: 128 does not divide 320)
    int nQ[4], qQ[4];
    #pragma unroll
    for (int r = 0; r < 4; ++r) {
        int m = m0 + wid * 16 + l4 * 4 + r;
        nQ[r] = m / NN_; qQ[r] = m - nQ[r] * NN_;
    }
    const int nV = arow / NN_, qV = arow - nV * NN_;

    const float* Ws[4] = {wq, wk, wv, wg};
    #pragma unroll
    for (int mat = 0; mat < 4; ++mat) {
        __syncthreads();
        const float* w = Ws[mat];
        // stage transposed bf16 weight: wl[j][k] = w[k][j], b64 LDS writes
        #pragma unroll
        for (int it = 0; it < 8; ++it) {
            int u  = tid + (it << 9);        // 4096 units
            int j  = u & 127, k4 = u >> 7;   // k4: 0..31
            bf16x4 t;
            t[0] = (bf16)w[(k4 * 4 + 0) * CZ_ + j];
            t[1] = (bf16)w[(k4 * 4 + 1) * CZ_ + j];
            t[2] = (bf16)w[(k4 * 4 + 2) * CZ_ + j];
            t[3] = (bf16)w[(k4 * 4 + 3) * CZ_ + j];
            *reinterpret_cast<bf16x4*>(&wl[j][k4 * 4]) = t;
        }
        __syncthreads();

        f32x4 zero = {0.f, 0.f, 0.f, 0.f};
        f32x4 acc[8];
        #pragma unroll
        for (int ct = 0; ct < 8; ++ct) acc[ct] = zero;

        #pragma unroll
        for (int ks = 0; ks < 4; ++ks) {
            #pragma unroll
            for (int ct = 0; ct < 8; ++ct) {
                bf16x8 wf = *reinterpret_cast<const bf16x8*>(&wl[ct * 16 + l15][ks * 32 + l4 * 8]);
                if (mat == 2)  // swapped: D[cout][m] so the V^T store coalesces
                    acc[ct] = __builtin_amdgcn_mfma_f32_16x16x32_bf16(wf, xf[ks], acc[ct], 0, 0, 0);
                else
                    acc[ct] = __builtin_amdgcn_mfma_f32_16x16x32_bf16(xf[ks], wf, acc[ct], 0, 0, 0);
            }
        }

        if (mat == 0) {
            #pragma unroll
            for (int ct = 0; ct < 8; ++ct) {
                const int cout = ct * 16 + l15, hh = cout >> 5, cc = cout & 31;
                #pragma unroll
                for (int r = 0; r < 4; ++r)
                    Qp[(size_t)((nQ[r] * H_ + hh) * NN_ + qQ[r]) * CH_ + cc] =
                        (bf16)(acc[ct][r] * 0.25500003540695464f);  // log2e/sqrt(32)
            }
        } else if (mat == 1) {
            #pragma unroll
            for (int ct = 0; ct < 8; ++ct) {
                const int cout = ct * 16 + l15, hh = cout >> 5, cc = cout & 31;
                #pragma unroll
                for (int r = 0; r < 4; ++r)
                    Kp[(size_t)((nQ[r] * H_ + hh) * NN_ + qQ[r]) * CH_ + cc] = (bf16)acc[ct][r];
            }
        } else if (mat == 2) {
            // D row = cout = ct*16 + l4*4 + r; D col = m-local = l15 (arow)
            #pragma unroll
            for (int ct = 0; ct < 8; ++ct) {
                #pragma unroll
                for (int r = 0; r < 4; ++r) {
                    const int cout = ct * 16 + l4 * 4 + r, hh = cout >> 5, cc = cout & 31;
                    Vp[(size_t)((nV * H_ + hh) * CH_ + cc) * NN_ + qV] = (bf16)acc[ct][r];
                }
            }
        } else {
            #pragma unroll
            for (int ct = 0; ct < 8; ++ct) {
                const int cout = ct * 16 + l15;
                const float bgj = bg[cout];
                #pragma unroll
                for (int r = 0; r < 4; ++r) {
                    float t = acc[ct][r] + bgj;
                    Gp[(size_t)(m0 + wid * 16 + l4 * 4 + r) * CZ_ + cout] =
                        (bf16)(1.0f / (1.0f + __expf(-t)));
                }
            }
        }
    }
}

// ---------------------------------------------------------------------------
// Kernel 2: fused attention + gating. grid 1280 = (n,h) blocks (h-major XCD
// pinning: one h per XCD -> 400KB bias slice L2-resident), 640 thr = 10 waves.
// K/V^T staged once in padded LDS (R7-proven). Wave = 32 q (2 x 16-q loop).
// VALU diet vs R7: scores arrive in exp2 domain (Q pre-scaled by log2e), so
// p = exp2(fma(bias, log2e, s)) -- one fma+exp per element. Row-sum l is
// accumulated on the MFMA pipe via a ones-A-fragment (sigma-invariant), which
// kills the per-body adds AND the final shuffles. Bias pipelined 2 bodies deep
// in static regs. s_setprio(1) around MFMA clusters. ~26 VALU/body (was ~41).
// Overwrites Gp with o*g (bf16).
// ---------------------------------------------------------------------------
__global__ __launch_bounds__(640, 2) void attn_kernel(
    const bf16* __restrict__ Qp, const bf16* __restrict__ Kp,
    const bf16* __restrict__ Vp, bf16* __restrict__ Gp,
    const float* __restrict__ bias)
{
    __shared__ bf16 Kl[320][40];    // 80B rows
    __shared__ bf16 Vl[32][344];    // 688B rows
    const int tid  = threadIdx.x;
    const int lane = tid & 63;
    const int wid  = tid >> 6;            // 0..9
    const int l15  = lane & 15, l4 = lane >> 4;
    const int gid = blockIdx.x;
    const int lin = (gid & 7) * 160 + (gid >> 3);
    const int h   = lin / NN_;
    const int n   = lin - h * NN_;

    const size_t nh = (size_t)(n * H_ + h);
    const bf16* Kh = Kp + nh * NN_ * CH_;
    const bf16* Vh = Vp + nh * CH_ * NN_;
    const bf16* Qh = Qp + nh * NN_ * CH_;

    // one-shot cooperative staging: 1280 16B chunks each for K and V^T
    #pragma unroll
    for (int i = 0; i < 2; ++i) {
        int c  = tid + i * 640;
        int kr = c >> 2, kc = (c & 3) * 8;
        *reinterpret_cast<bf16x8*>(&Kl[kr][kc]) =
            *reinterpret_cast<const bf16x8*>(Kh + kr * CH_ + kc);
        int vr = c / 40, vc = (c % 40) * 8;
        *reinterpret_cast<bf16x8*>(&Vl[vr][vc]) =
            *reinterpret_cast<const bf16x8*>(Vh + vr * NN_ + vc);
    }
    __syncthreads();

    const f32x4 zero = {0.f, 0.f, 0.f, 0.f};
    bf16x8 onesf;
    #pragma unroll
    for (int i = 0; i < 8; ++i) onesf[i] = (bf16)1.0f;

    #pragma unroll 1
    for (int qg = 0; qg < 2; ++qg) {
        const int qb = wid * 32 + qg * 16;
        const bf16x8 qf = *reinterpret_cast<const bf16x8*>(&Qh[(qb + l15) * CH_ + l4 * 8]);
        const float* bq = bias + ((size_t)h * NN_ + qb + l15) * NN_ + l4 * 4;
        const size_t gbase = ((size_t)n * NN_ + qb + l15) * CZ_ + h * CH_;
        const bf16x4 g0 = *reinterpret_cast<const bf16x4*>(&Gp[gbase + l4 * 4]);
        const bf16x4 g1 = *reinterpret_cast<const bf16x4*>(&Gp[gbase + 16 + l4 * 4]);

        f32x4 o0 = zero, o1 = zero, ol = zero;

        // 2-deep bias pipeline in STATIC named buffers
        float4 bA0 = *reinterpret_cast<const float4*>(bq);
        float4 bA1 = *reinterpret_cast<const float4*>(bq + 16);
        float4 bB0 = *reinterpret_cast<const float4*>(bq + 32);
        float4 bB1 = *reinterpret_cast<const float4*>(bq + 48);

#define ATTN_TP(TP, B0, B1, PRE)                                                   \
    {                                                                              \
        const int kvm = (TP) * 32;                                                 \
        bf16x8 kf0 = *reinterpret_cast<const bf16x8*>(&Kl[kvm + l15][l4 * 8]);     \
        bf16x8 kf1 = *reinterpret_cast<const bf16x8*>(&Kl[kvm + 16 + l15][l4 * 8]);\
        __builtin_amdgcn_s_setprio(1);                                             \
        f32x4 s0 = __builtin_amdgcn_mfma_f32_16x16x32_bf16(kf0, qf, zero, 0, 0, 0);\
        f32x4 s1 = __builtin_amdgcn_mfma_f32_16x16x32_bf16(kf1, qf, zero, 0, 0, 0);\
        __builtin_amdgcn_s_setprio(0);                                             \
        float p0 = __builtin_amdgcn_exp2f(__builtin_fmaf(B0.x, LOG2E_, s0[0]));    \
        float p1 = __builtin_amdgcn_exp2f(__builtin_fmaf(B0.y, LOG2E_, s0[1]));    \
        float p2 = __builtin_amdgcn_exp2f(__builtin_fmaf(B0.z, LOG2E_, s0[2]));    \
        float p3 = __builtin_amdgcn_exp2f(__builtin_fmaf(B0.w, LOG2E_, s0[3]));    \
        float p4 = __builtin_amdgcn_exp2f(__builtin_fmaf(B1.x, LOG2E_, s1[0]));    \
        float p5 = __builtin_amdgcn_exp2f(__builtin_fmaf(B1.y, LOG2E_, s1[1]));    \
        float p6 = __builtin_amdgcn_exp2f(__builtin_fmaf(B1.z, LOG2E_, s1[2]));    \
        float p7 = __builtin_amdgcn_exp2f(__builtin_fmaf(B1.w, LOG2E_, s1[3]));    \
        u32x4 ww;                                                                  \
        ww[0] = pack_bf16(p0, p1); ww[1] = pack_bf16(p2, p3);                      \
        ww[2] = pack_bf16(p4, p5); ww[3] = pack_bf16(p6, p7);                      \
        bf16x8 pf = __builtin_bit_cast(bf16x8, ww);                                \
        if (PRE) { /* refill for TP+2 */                                           \
            B0 = *reinterpret_cast<const float4*>(bq + ((TP) + 2) * 32);           \
            B1 = *reinterpret_cast<const float4*>(bq + ((TP) + 2) * 32 + 16);      \
        }                                                                          \
        bf16x4 va0 = *reinterpret_cast<const bf16x4*>(&Vl[l15][kvm + l4 * 4]);     \
        bf16x4 va1 = *reinterpret_cast<const bf16x4*>(&Vl[l15][kvm + 16 + l4 * 4]);\
        bf16x4 vb0 = *reinterpret_cast<const bf16x4*>(&Vl[16 + l15][kvm + l4 * 4]);\
        bf16x4 vb1 = *reinterpret_cast<const bf16x4*>(&Vl[16 + l15][kvm + 16 + l4 * 4]); \
        bf16x8 vf0 = __builtin_shufflevector(va0, va1, 0, 1, 2, 3, 4, 5, 6, 7);    \
        bf16x8 vf1 = __builtin_shufflevector(vb0, vb1, 0, 1, 2, 3, 4, 5, 6, 7);    \
        __builtin_amdgcn_s_setprio(1);                                             \
        ol = __builtin_amdgcn_mfma_f32_16x16x32_bf16(onesf, pf, ol, 0, 0, 0);      \
        o0 = __builtin_amdgcn_mfma_f32_16x16x32_bf16(vf0, pf, o0, 0, 0, 0);        \
        o1 = __builtin_amdgcn_mfma_f32_16x16x32_bf16(vf1, pf, o1, 0, 0, 0);        \
        __builtin_amdgcn_s_setprio(0);                                             \
    }

        #pragma unroll 1
        for (int t2 = 0; t2 < 4; ++t2) {
            ATTN_TP(2 * t2,     bA0, bA1, true);
            ATTN_TP(2 * t2 + 1, bB0, bB1, true);
        }
        ATTN_TP(8, bA0, bA1, false);
        ATTN_TP(9, bB0, bB1, false);
#undef ATTN_TP

        // ol[r] holds the full row-sum l for q = l15 (all r identical)
        const float linv = 1.0f / ol[0];

        bf16x4 h0, h1;
        #pragma unroll
        for (int r = 0; r < 4; ++r) {
            h0[r] = (bf16)(o0[r] * linv * (float)g0[r]);
            h1[r] = (bf16)(o1[r] * linv * (float)g1[r]);
        }
        *reinterpret_cast<bf16x4*>(&Gp[gbase + l4 * 4]) = h0;
        *reinterpret_cast<bf16x4*>(&Gp[gbase + 16 + l4 * 4]) = h1;
    }
}

// ---------------------------------------------------------------------------
// Kernel 3: out = og @ wo + bo (fp32). grid 800 x 512 threads.
// ---------------------------------------------------------------------------
__global__ __launch_bounds__(512) void oproj_kernel(
    const bf16* __restrict__ og, const float* __restrict__ wo,
    const float* __restrict__ bo, float* __restrict__ out)
{
    __shared__ bf16 wl[128][136];
    const int tid  = threadIdx.x;
    const int lane = tid & 63, wid = tid >> 6;
    const int l15  = lane & 15, l4 = lane >> 4;
    const int m0   = blockIdx.x << 7;

    #pragma unroll
    for (int it = 0; it < 8; ++it) {
        int u  = tid + (it << 9);
        int j  = u & 127, k4 = u >> 7;
        bf16x4 t;
        t[0] = (bf16)wo[(k4 * 4 + 0) * CZ_ + j];
        t[1] = (bf16)wo[(k4 * 4 + 1) * CZ_ + j];
        t[2] = (bf16)wo[(k4 * 4 + 2) * CZ_ + j];
        t[3] = (bf16)wo[(k4 * 4 + 3) * CZ_ + j];
        *reinterpret_cast<bf16x4*>(&wl[j][k4 * 4]) = t;
    }
    __syncthreads();

    const int arow = m0 + wid * 16 + l15;
    bf16x8 af[4];
    #pragma unroll
    for (int ks = 0; ks < 4; ++ks)
        af[ks] = *reinterpret_cast<const bf16x8*>(&og[(size_t)arow * CZ_ + ks * 32 + l4 * 8]);

    f32x4 zero = {0.f, 0.f, 0.f, 0.f};
    f32x4 acc[8];
    #pragma unroll
    for (int ct = 0; ct < 8; ++ct) acc[ct] = zero;
    #pragma unroll
    for (int ks = 0; ks < 4; ++ks)
        #pragma unroll
        for (int ct = 0; ct < 8; ++ct) {
            bf16x8 wf = *reinterpret_cast<const bf16x8*>(&wl[ct * 16 + l15][ks * 32 + l4 * 8]);
            acc[ct] = __builtin_amdgcn_mfma_f32_16x16x32_bf16(af[ks], wf, acc[ct], 0, 0, 0);
        }

    #pragma unroll
    for (int ct = 0; ct < 8; ++ct) {
        const int cout = ct * 16 + l15;
        const float bov = bo[cout];
        #pragma unroll
        for (int r = 0; r < 4; ++r)
            out[(size_t)(m0 + wid * 16 + l4 * 4 + r) * CZ_ + cout] = acc[ct][r] + bov;
    }
}

// ---------------------------------------------------------------------------
extern "C" void kernel_launch(void* const* d_in, const int* in_sizes, int n_in,
                              void* d_out, int out_size, void* d_ws, size_t ws_size,
                              hipStream_t stream) {
    (void)in_sizes; (void)n_in; (void)out_size; (void)ws_size;
    const float* x    = (const float*)d_in[0];
    const float* bias = (const float*)d_in[1];
    const float* wq   = (const float*)d_in[2];
    const float* wk   = (const float*)d_in[3];
    const float* wv   = (const float*)d_in[4];
    const float* wg   = (const float*)d_in[5];
    const float* bg   = (const float*)d_in[6];
    const float* wo   = (const float*)d_in[7];
    const float* bo   = (const float*)d_in[8];
    float* out = (float*)d_out;

    const size_t ELEMS = (size_t)NN_ * NN_ * CZ_;
    bf16* Qp = (bf16*)d_ws;          // 26.2 MB
    bf16* Gp = Qp + ELEMS;           // 26.2 MB
    bf16* Kp = (bf16*)d_out;         // scratch until oproj overwrites
    bf16* Vp = Kp + ELEMS;

    qkvg_kernel<<<dim3(800), 512, 0, stream>>>(x, wq, wk, wv, wg, bg, Qp, Kp, Vp, Gp);
    attn_kernel<<<dim3(1280), 640, 0, stream>>>(Qp, Kp, Vp, Gp, bias);
    oproj_kernel<<<dim3(800), 512, 0, stream>>>(Gp, wo, bo, out);
}